// Round 7
// baseline (732.216 us; speedup 1.0000x reference)
//
#include <hip/hip_runtime.h>

#define NB 16
#define TT 8192
#define Bb 4
#define NWGX 64      // T / 128 tiles along time

typedef __attribute__((ext_vector_type(8))) short short8;
typedef __attribute__((ext_vector_type(16))) float f32x16;

__device__ __forceinline__ unsigned short bf16_rn(float f) {
  unsigned int u = __float_as_uint(f);
  u += 0x7FFF + ((u >> 16) & 1);
  return (unsigned short)(u >> 16);
}
// within-16-chunk k -> stored position (same permute on both GEMM operands)
__device__ __forceinline__ int kpos(int k) {
  int g = (k >> 2) & 1;
  int e = (k & 3) + 4 * (k >> 3);
  return g * 8 + e;
}
__device__ __forceinline__ int kinv(int p) {
  int g = p >> 3, e = p & 7;
  return (e & 3) + 4 * g + 8 * (e >> 2);
}

// all threads spin; acquire-poll (few iterations expected: neighbor runs in
// lockstep, flag is usually already set on first look)
__device__ __forceinline__ void wait_flag(const unsigned* f) {
  while (__hip_atomic_load(f, __ATOMIC_ACQUIRE, __HIP_MEMORY_SCOPE_AGENT) == 0u) {
    __builtin_amdgcn_s_sleep(8);
  }
}

// ---------------------------------------------------------------------------
// All weights fp32 -> bf16, k-permuted. One launch. (validated round 4)
__global__ __launch_bounds__(256) void prep_weights(
    const float* __restrict__ wconv, const float* __restrict__ wres,
    const float* __restrict__ wsk, const float* __restrict__ w1,
    const float* __restrict__ w2, short* __restrict__ dwc,
    short* __restrict__ dwr, short* __restrict__ dws,
    short* __restrict__ dw1, short* __restrict__ dw2)
{
  int i = blockIdx.x * 256 + threadIdx.x;
  if (i < 262144) {
    int k = kinv(i & 15);
    int ic = (i & 48) | k;
    int oc = (i >> 6) & 127;
    int tap = (i >> 13) & 1;
    int blk = i >> 14;
    dwc[i] = (short)bf16_rn(wconv[(((blk * 128 + oc) * 64 + ic) << 1) | tap]);
    return;
  }
  int j = i - 262144;
  if (j < 65536) { dwr[j] = (short)bf16_rn(wres[(j & ~15) | kinv(j & 15)]); return; }
  j -= 65536;
  if (j < 262144) { dws[j] = (short)bf16_rn(wsk[(j & ~15) | kinv(j & 15)]); return; }
  j -= 262144;
  if (j < 65536) { dw1[j] = (short)bf16_rn(w1[(j & ~15) | kinv(j & 15)]); return; }
  j -= 65536;
  if (j < 65536) { dw2[j] = (short)bf16_rn(w2[(j & ~15) | kinv(j & 15)]); return; }
}

// ---------------------------------------------------------------------------
// Fused megakernel: embed + 16 blocks + head. Grid (64,4) = 256 WGs, 512 thr.
// Inter-WG sync: per-(block,b,gx) halo slots + release/acquire flags
// (left-neighbor only — no grid barrier).
__global__ __launch_bounds__(512, 1) void mega_kernel(
    const int* __restrict__ x, const float* __restrict__ h,
    const float* __restrict__ embed,
    const short* __restrict__ wc, const short* __restrict__ wr,
    const short* __restrict__ wsk, const short* __restrict__ w1,
    const short* __restrict__ w2,
    unsigned short* __restrict__ halo,   // [NB][Bb][NWGX][128][64] bf16
    unsigned* __restrict__ flags,        // [NB][Bb][NWGX]
    float* __restrict__ out)
{
  __shared__ __align__(16) char smem[131072];
  float* rs  = (float*)smem;            // [128][64] fp32 resid (persistent)
  short* win = (short*)(smem + 32768);  // [256][64] swizzled conv window
  short* zl  = (short*)(smem + 65536);  // [128][64] swizzled z
  short* yb  = (short*)smem;            // head: [128][256] swizzled (64K)
  short* y2b = (short*)(smem + 65536);  // head: [128][256] swizzled (64K)

  const int b = blockIdx.y;
  const int gx = blockIdx.x;
  const int t0 = gx * 128;
  const int tid = threadIdx.x;
  const int lane = tid & 63, wv = tid >> 6;
  const int l31 = lane & 31, hi = lane >> 5;

  // ---- prologue: embed -> rs; publish row 127 (block 0 halo, dil=1) ----
  {
    const int* xb = x + b * TT + t0;
#pragma unroll
    for (int it = 0; it < 16; ++it) {
      int u = it * 512 + tid;
      int c = u & 63, t = u >> 6;
      rs[t * 64 + c] = embed[(size_t)xb[t] * 64 + c];
    }
    __syncthreads();
    if (gx < NWGX - 1) {
      if (tid < 32) {
        int c0 = tid * 2;
        unsigned int v = (unsigned int)bf16_rn(rs[127 * 64 + c0]) |
                         ((unsigned int)bf16_rn(rs[127 * 64 + c0 + 1]) << 16);
        int p0 = (c0 & 48) | kpos(c0 & 15);
        unsigned short* slot = halo + ((size_t)(0 * Bb + b) * NWGX + gx) * 8192;
        *(unsigned int*)(slot + 127 * 64 + p0) = v;
      }
      __syncthreads();   // drain the publish store (barrier waits vmcnt 0)
      if (tid == 0)
        __hip_atomic_store(&flags[(0 * Bb + b) * NWGX + gx], 1u,
                           __ATOMIC_RELEASE, __HIP_MEMORY_SCOPE_AGENT);
    }
  }

  // skip accumulators: D[row=t (4 tiles)][col=sk = wv*32+l31]
  f32x16 s0 = {}, s1 = {}, s2 = {}, s3 = {};

  for (int i = 0; i < NB; ++i) {
    const int dil = 1 << (i & 7);

    // ---- issue h loads FIRST (latency hides under staging) ----
    const int pr = wv >> 2, nt = wv & 3;
    const int tloc = nt * 32 + l31, tcol = t0 + tloc;
    f32x16 aA, aS;
    const float* hb = h + ((size_t)b * 2048 + (size_t)i * 128) * TT;
#pragma unroll
    for (int r = 0; r < 16; ++r) {
      int row = (r & 3) + 4 * hi + 8 * (r >> 2) + 32 * pr;  // 0..63
      aA[r] = hb[(size_t)row * TT + tcol];
      aS[r] = hb[(size_t)(row + 64) * TT + tcol];
    }

    // ---- halo: wait left neighbor's flag, stage rows [128-dil,128) ----
    if (gx > 0) {
      wait_flag(&flags[((size_t)i * Bb + b) * NWGX + gx - 1]);
      const unsigned short* hs =
          halo + (((size_t)i * Bb + b) * NWGX + gx - 1) * 8192;
      for (int u = tid; u < dil * 8; u += 512) {
        int q = u & 7, w = 128 - dil + (u >> 3);
        short8 v = *(const short8*)(hs + w * 64 + q * 8);
        unsigned int byte = (unsigned int)(w * 128 + q * 16) ^
                            (unsigned int)((w & 7) << 4);
        *(short8*)((char*)win + byte) = v;
      }
    } else {
      for (int u = tid; u < dil * 8; u += 512) {
        int q = u & 7, w = 128 - dil + (u >> 3);
        short8 v = {};
        unsigned int byte = (unsigned int)(w * 128 + q * 16) ^
                            (unsigned int)((w & 7) << 4);
        *(short8*)((char*)win + byte) = v;
      }
    }
    // ---- stage own rows [128,256) from rs (fp32 -> packed bf16) ----
#pragma unroll
    for (int it = 0; it < 8; ++it) {
      int u = it * 512 + tid;  // 128 rows x 32 pairs
      int cpair = u & 31, t = u >> 5;
      int c0 = cpair * 2;
      unsigned int v = (unsigned int)bf16_rn(rs[t * 64 + c0]) |
                       ((unsigned int)bf16_rn(rs[t * 64 + c0 + 1]) << 16);
      int p0 = (c0 & 48) | kpos(c0 & 15);
      int w = t + 128;
      unsigned int byte = (unsigned int)(w * 128 + p0 * 2) ^
                          (unsigned int)((w & 7) << 4);
      *(unsigned int*)((char*)win + byte) = v;
    }
    __syncthreads();

    // ---- conv: two K=64 tap GEMMs on the window (acc pre-init from h) ----
    const short* wA0 = wc + (size_t)i * 16384 + (32 * pr + l31) * 64;  // tap0
    const short* wA1 = wA0 + 8192;                                      // tap1
    const int r1 = tloc + 128, r0 = tloc + 128 - dil;
#pragma unroll
    for (int ks = 0; ks < 4; ++ks) {
      int off = ks * 16 + 8 * hi;
      short8 b1 = *(const short8*)((char*)win +
          ((unsigned int)(r1 * 128 + off * 2) ^ (unsigned int)((r1 & 7) << 4)));
      short8 b0 = *(const short8*)((char*)win +
          ((unsigned int)(r0 * 128 + off * 2) ^ (unsigned int)((r0 & 7) << 4)));
      short8 a0t = *(const short8*)(wA0 + off);
      short8 a1t = *(const short8*)(wA1 + off);
      short8 a0s = *(const short8*)(wA0 + 4096 + off);
      short8 a1s = *(const short8*)(wA1 + 4096 + off);
      aA = __builtin_amdgcn_mfma_f32_32x32x16_bf16(a0t, b0, aA, 0, 0, 0);
      aA = __builtin_amdgcn_mfma_f32_32x32x16_bf16(a1t, b1, aA, 0, 0, 0);
      aS = __builtin_amdgcn_mfma_f32_32x32x16_bf16(a0s, b0, aS, 0, 0, 0);
      aS = __builtin_amdgcn_mfma_f32_32x32x16_bf16(a1s, b1, aS, 0, 0, 0);
    }

    // ---- gated activation -> zl ----
#pragma unroll
    for (int r = 0; r < 16; r += 2) {
      int ic0 = (r & 3) + 4 * hi + 8 * (r >> 2) + 32 * pr;
      float z0 = (1.f - 2.f / (__expf(2.f * aA[r]) + 1.f)) *
                 (1.f / (1.f + __expf(-aS[r])));
      float z1 = (1.f - 2.f / (__expf(2.f * aA[r + 1]) + 1.f)) *
                 (1.f / (1.f + __expf(-aS[r + 1])));
      unsigned int v = (unsigned int)bf16_rn(z0) | ((unsigned int)bf16_rn(z1) << 16);
      int p = (ic0 & ~15) | kpos(ic0 & 15);
      unsigned int byte = (unsigned int)(tloc * 128 + p * 2) ^
                          (unsigned int)((tloc & 7) << 4);
      *(unsigned int*)((char*)zl + byte) = v;
    }
    __syncthreads();

    // ---- skip accumulation: s[mt][sk=wv*32+l31] += z @ wsk_i^T ----
    {
      const short* wb = wsk + (size_t)i * 16384 + (wv * 32 + l31) * 64;
#define SKIP_MT(SS, MT)                                                        \
  {                                                                            \
    const int trow = (MT)*32 + l31;                                            \
    _Pragma("unroll") for (int ks = 0; ks < 4; ++ks) {                         \
      int off = ks * 16 + 8 * hi;                                              \
      short8 bw = *(const short8*)(wb + off);                                  \
      short8 az = *(const short8*)((char*)zl +                                 \
          ((unsigned int)(trow * 128 + off * 2) ^                              \
           (unsigned int)((trow & 7) << 4)));                                  \
      SS = __builtin_amdgcn_mfma_f32_32x32x16_bf16(az, bw, SS, 0, 0, 0);       \
    }                                                                          \
  }
      SKIP_MT(s0, 0) SKIP_MT(s1, 1) SKIP_MT(s2, 2) SKIP_MT(s3, 3)
#undef SKIP_MT
    }

    if (i < NB - 1) {
      // ---- residual: rs += z @ wres^T (D[row=t][col=oc]) ----
      const int mt = wv >> 1, ntr = wv & 1;
      const int trow = mt * 32 + l31;
      f32x16 ar = {};
      const short* wrb = wr + (size_t)i * 4096 + (ntr * 32 + l31) * 64;
#pragma unroll
      for (int ks = 0; ks < 4; ++ks) {
        int off = ks * 16 + 8 * hi;
        short8 az = *(const short8*)((char*)zl +
            ((unsigned int)(trow * 128 + off * 2) ^ (unsigned int)((trow & 7) << 4)));
        short8 bw = *(const short8*)(wrb + off);
        ar = __builtin_amdgcn_mfma_f32_32x32x16_bf16(az, bw, ar, 0, 0, 0);
      }
#pragma unroll
      for (int r = 0; r < 16; ++r) {
        int t = mt * 32 + (r & 3) + 4 * hi + 8 * (r >> 2);
        int oc = ntr * 32 + l31;
        rs[t * 64 + oc] += ar[r];
      }
      __syncthreads();  // rs update visible before publish

      // ---- publish tail rows for right neighbor's block i+1 halo ----
      if (gx < NWGX - 1) {
        const int nd0 = 1 << ((i + 1) & 7);
        const int nd = nd0 < 128 ? nd0 : 128;
        unsigned short* slot =
            halo + (((size_t)(i + 1) * Bb + b) * NWGX + gx) * 8192;
        for (int u = tid; u < nd * 32; u += 512) {
          int cpair = u & 31, row = 128 - nd + (u >> 5);
          int c0 = cpair * 2;
          unsigned int v = (unsigned int)bf16_rn(rs[row * 64 + c0]) |
                           ((unsigned int)bf16_rn(rs[row * 64 + c0 + 1]) << 16);
          int p0 = (c0 & 48) | kpos(c0 & 15);
          *(unsigned int*)(slot + row * 64 + p0) = v;
        }
        __syncthreads();  // drain publish stores before flag
        if (tid == 0)
          __hip_atomic_store(&flags[((size_t)(i + 1) * Bb + b) * NWGX + gx], 1u,
                             __ATOMIC_RELEASE, __HIP_MEMORY_SCOPE_AGENT);
      }
    }
  }

  // ================= head (same WG, LDS reused) =================
  __syncthreads();

  // relu(skip) -> yb [128][256] k-permuted swizzled
  {
    int sk = wv * 32 + l31;
    int p = (sk & 0xF0) | kpos(sk & 15);
#define RELU_MT(SS, MT)                                                        \
  {                                                                            \
    _Pragma("unroll") for (int r = 0; r < 16; ++r) {                           \
      int dt = (MT)*32 + (r & 3) + 4 * hi + 8 * (r >> 2);                      \
      unsigned int byte =                                                      \
          (unsigned int)(dt * 512 + p * 2) ^ (unsigned int)((dt & 7) << 4);    \
      *(short*)((char*)yb + byte) = (short)bf16_rn(fmaxf(SS[r], 0.f));         \
    }                                                                          \
  }
    RELU_MT(s0, 0) RELU_MT(s1, 1) RELU_MT(s2, 2) RELU_MT(s3, 3)
#undef RELU_MT
  }
  __syncthreads();

  // y2 = relu(w1 @ y): D[row=o][col=t] -> y2b transposed [t][op]
  {
    const short* w1r = w1 + (wv * 32 + l31) * 256;
#pragma unroll
    for (int ntile = 0; ntile < 4; ++ntile) {
      const int trow = ntile * 32 + l31;
      f32x16 acc = {};
#pragma unroll
      for (int ks = 0; ks < 16; ++ks) {
        int off = ks * 16 + 8 * hi;
        short8 by = *(const short8*)((char*)yb +
            ((unsigned int)(trow * 512 + off * 2) ^ (unsigned int)((trow & 7) << 4)));
        short8 aw = *(const short8*)(w1r + off);
        acc = __builtin_amdgcn_mfma_f32_32x32x16_bf16(aw, by, acc, 0, 0, 0);
      }
#pragma unroll
      for (int r = 0; r < 16; r += 2) {
        int o0 = wv * 32 + (r & 3) + 4 * hi + 8 * (r >> 2);
        unsigned int v = (unsigned int)bf16_rn(fmaxf(acc[r], 0.f)) |
                         ((unsigned int)bf16_rn(fmaxf(acc[r + 1], 0.f)) << 16);
        int p = (o0 & 0xF0) | kpos(o0 & 15);
        unsigned int byte = (unsigned int)(trow * 512 + p * 2) ^
                            (unsigned int)((trow & 7) << 4);
        *(unsigned int*)((char*)y2b + byte) = v;
      }
    }
  }
  __syncthreads();

  // out = w2 @ y2: D[row=oc][col=t], coalesced [B][OUT][T] write
  {
    const short* w2r = w2 + (wv * 32 + l31) * 256;
    float* ob = out + (size_t)b * 256 * TT;
#pragma unroll
    for (int ntile = 0; ntile < 4; ++ntile) {
      const int trow = ntile * 32 + l31;
      f32x16 acc = {};
#pragma unroll
      for (int ks = 0; ks < 16; ++ks) {
        int off = ks * 16 + 8 * hi;
        short8 by = *(const short8*)((char*)y2b +
            ((unsigned int)(trow * 512 + off * 2) ^ (unsigned int)((trow & 7) << 4)));
        short8 aw = *(const short8*)(w2r + off);
        acc = __builtin_amdgcn_mfma_f32_32x32x16_bf16(aw, by, acc, 0, 0, 0);
      }
#pragma unroll
      for (int r = 0; r < 16; ++r) {
        int oc = wv * 32 + (r & 3) + 4 * hi + 8 * (r >> 2);
        ob[(size_t)oc * TT + t0 + trow] = acc[r];
      }
    }
  }
}

// ---------------------------------------------------------------------------
extern "C" void kernel_launch(void* const* d_in, const int* in_sizes, int n_in,
                              void* d_out, int out_size, void* d_ws, size_t ws_size,
                              hipStream_t stream)
{
  const int* x = (const int*)d_in[0];
  const float* h = (const float*)d_in[1];
  const float* embed = (const float*)d_in[2];
  const float* w_conv = (const float*)d_in[3];
  const float* w_res = (const float*)d_in[4];
  const float* w_skip = (const float*)d_in[5];
  const float* w_out1 = (const float*)d_in[6];
  const float* w_out2 = (const float*)d_in[7];
  float* out = (float*)d_out;

  char* ws = (char*)d_ws;
  unsigned short* halo = (unsigned short*)ws;                    // 64 MiB
  unsigned* flags = (unsigned*)(ws + ((size_t)64 << 20));        // 16 KB
  short* dwc = (short*)(ws + ((size_t)65 << 20));                // 512 KB
  short* dwr = dwc + 262144;
  short* dws = dwr + 65536;
  short* dw1 = dws + 262144;
  short* dw2 = dw1 + 65536;

  hipMemsetAsync(flags, 0, NB * Bb * NWGX * sizeof(unsigned), stream);
  prep_weights<<<2816, 256, 0, stream>>>(w_conv, w_res, w_skip, w_out1, w_out2,
                                         dwc, dwr, dws, dw1, dw2);
  mega_kernel<<<dim3(NWGX, Bb), 512, 0, stream>>>(
      x, h, embed, dwc, dwr, dws, dw1, dw2, halo, flags, out);
}

// Round 8
// 383.989 us; speedup vs baseline: 1.9069x; 1.9069x over previous
//
#include <hip/hip_runtime.h>

#define NB 16
#define TT 8192
#define Bb 4

typedef __attribute__((ext_vector_type(8))) short short8;
typedef __attribute__((ext_vector_type(16))) float f32x16;

__device__ __forceinline__ unsigned short bf16_rn(float f) {
  unsigned int u = __float_as_uint(f);
  u += 0x7FFF + ((u >> 16) & 1);
  return (unsigned short)(u >> 16);
}
__device__ __forceinline__ unsigned int pack2(float a, float b) {
  return (unsigned int)bf16_rn(a) | ((unsigned int)bf16_rn(b) << 16);
}
// within-16-chunk k -> stored position (same permute on both GEMM operands)
__device__ __forceinline__ int kpos(int k) {
  int g = (k >> 2) & 1;
  int e = (k & 3) + 4 * (k >> 3);
  return g * 8 + e;
}
__device__ __forceinline__ int kinv(int p) {
  int g = p >> 3, e = p & 7;
  return (e & 3) + 4 * g + 8 * (e >> 2);
}

// ---------------------------------------------------------------------------
// All weights fp32 -> bf16, k-permuted. One launch. (validated round 4)
__global__ __launch_bounds__(256) void prep_weights(
    const float* __restrict__ wconv, const float* __restrict__ wres,
    const float* __restrict__ wsk, const float* __restrict__ w1,
    const float* __restrict__ w2, short* __restrict__ dwc,
    short* __restrict__ dwr, short* __restrict__ dws,
    short* __restrict__ dw1, short* __restrict__ dw2)
{
  int i = blockIdx.x * 256 + threadIdx.x;
  if (i < 262144) {
    int k = kinv(i & 15);
    int ic = (i & 48) | k;
    int oc = (i >> 6) & 127;
    int tap = (i >> 13) & 1;
    int blk = i >> 14;
    dwc[i] = (short)bf16_rn(wconv[(((blk * 128 + oc) * 64 + ic) << 1) | tap]);
    return;
  }
  int j = i - 262144;
  if (j < 65536) { dwr[j] = (short)bf16_rn(wres[(j & ~15) | kinv(j & 15)]); return; }
  j -= 65536;
  if (j < 262144) { dws[j] = (short)bf16_rn(wsk[(j & ~15) | kinv(j & 15)]); return; }
  j -= 262144;
  if (j < 65536) { dw1[j] = (short)bf16_rn(w1[(j & ~15) | kinv(j & 15)]); return; }
  j -= 65536;
  if (j < 65536) { dw2[j] = (short)bf16_rn(w2[(j & ~15) | kinv(j & 15)]); return; }
}

// ---------------------------------------------------------------------------
// One WaveNet block. Tile = 32 t-rows, 128 threads (2 waves), grid (256, 4).
// blk==0 gathers embed directly (no separate embed kernel / resid-in read).
__global__ __launch_bounds__(128) void block_kernel(
    const float* __restrict__ rin, float* __restrict__ rout,
    const int* __restrict__ x, const float* __restrict__ embed,
    const float* __restrict__ h, const short* __restrict__ wc,
    const short* __restrict__ wr, unsigned short* __restrict__ zg,
    int blk, int dil, int last)
{
  __shared__ short win[160 * 64];  // rows [0,dil)=halo, [dil,dil+32)=own; 20KB
  __shared__ float rs[32 * 64];    // own tile fp32 (for residual add);  8KB
  __shared__ short zl[32 * 64];    // z, swizzled k-permuted;            4KB

  const int b = blockIdx.y;
  const int t0 = blockIdx.x * 32;
  const int tid = threadIdx.x;
  const int lane = tid & 63, wv = tid >> 6;   // wv in {0,1}
  const int l31 = lane & 31, hi = lane >> 5;

  // ---- h loads issued first (latency hides under staging) ----
  const int tcol = t0 + l31;
  f32x16 aA, aS;
  const float* hb = h + ((size_t)b * 2048 + (size_t)blk * 128) * TT;
#pragma unroll
  for (int r = 0; r < 16; ++r) {
    int row = (r & 3) + 4 * hi + 8 * (r >> 2) + 32 * wv;  // 0..63
    aA[r] = hb[(size_t)row * TT + tcol];
    aS[r] = hb[(size_t)(row + 64) * TT + tcol];
  }

  // ---- stage window (+ own fp32 into rs) ----
  if (blk == 0) {
    const int* xb = x + b * TT;
#pragma unroll
    for (int it = 0; it < 8; ++it) {
      int u = it * 128 + tid;           // 32 rows x 32 pairs
      int cpair = u & 31, t = u >> 5;
      int c0 = cpair * 2;
      int xi = xb[t0 + t];
      float v0 = embed[(size_t)xi * 64 + c0];
      float v1 = embed[(size_t)xi * 64 + c0 + 1];
      rs[t * 64 + c0] = v0;
      rs[t * 64 + c0 + 1] = v1;
      int p0 = (c0 & 48) | kpos(c0 & 15);
      int w = dil + t;                  // dil == 1
      unsigned int byte = (unsigned int)(w * 128 + p0 * 2) ^
                          (unsigned int)((w & 7) << 4);
      *(unsigned int*)((char*)win + byte) = pack2(v0, v1);
    }
    if (tid < 32) {                     // halo row t0-1
      int c0 = tid * 2;
      float v0 = 0.f, v1 = 0.f;
      if (t0 > 0) {
        int xi = xb[t0 - 1];
        v0 = embed[(size_t)xi * 64 + c0];
        v1 = embed[(size_t)xi * 64 + c0 + 1];
      }
      int p0 = (c0 & 48) | kpos(c0 & 15);
      unsigned int byte = (unsigned int)(p0 * 2);   // w = 0
      *(unsigned int*)((char*)win + byte) = pack2(v0, v1);
    }
  } else {
    const float* rbase = rin + (size_t)b * TT * 64;
#pragma unroll
    for (int it = 0; it < 8; ++it) {
      int u = it * 128 + tid;
      int cpair = u & 31, t = u >> 5;
      int c0 = cpair * 2;
      float2 f = *(const float2*)(rbase + (size_t)(t0 + t) * 64 + c0);
      rs[t * 64 + c0] = f.x;
      rs[t * 64 + c0 + 1] = f.y;
      int p0 = (c0 & 48) | kpos(c0 & 15);
      int w = dil + t;
      unsigned int byte = (unsigned int)(w * 128 + p0 * 2) ^
                          (unsigned int)((w & 7) << 4);
      *(unsigned int*)((char*)win + byte) = pack2(f.x, f.y);
    }
    for (int u = tid; u < dil * 32; u += 128) {   // halo rows [t0-dil, t0)
      int cpair = u & 31, w = u >> 5;
      int c0 = cpair * 2;
      int gt = t0 - dil + w;
      float2 f = {0.f, 0.f};
      if (gt >= 0) f = *(const float2*)(rbase + (size_t)gt * 64 + c0);
      int p0 = (c0 & 48) | kpos(c0 & 15);
      unsigned int byte = (unsigned int)(w * 128 + p0 * 2) ^
                          (unsigned int)((w & 7) << 4);
      *(unsigned int*)((char*)win + byte) = pack2(f.x, f.y);
    }
  }
  __syncthreads();

  // ---- conv: two K=64 tap GEMMs (acc pre-init from h). D[row=oc][col=t] ----
  const short* wA0 = wc + (size_t)blk * 16384 + (32 * wv + l31) * 64;  // tap0
  const short* wA1 = wA0 + 8192;                                       // tap1
  const int r1 = dil + l31;   // x[t]
  const int r0 = l31;         // x[t-dil]
#pragma unroll
  for (int ks = 0; ks < 4; ++ks) {
    int off = ks * 16 + 8 * hi;
    short8 b1 = *(const short8*)((char*)win +
        ((unsigned int)(r1 * 128 + off * 2) ^ (unsigned int)((r1 & 7) << 4)));
    short8 b0 = *(const short8*)((char*)win +
        ((unsigned int)(r0 * 128 + off * 2) ^ (unsigned int)((r0 & 7) << 4)));
    short8 a0t = *(const short8*)(wA0 + off);
    short8 a1t = *(const short8*)(wA1 + off);
    short8 a0s = *(const short8*)(wA0 + 4096 + off);
    short8 a1s = *(const short8*)(wA1 + 4096 + off);
    aA = __builtin_amdgcn_mfma_f32_32x32x16_bf16(a0t, b0, aA, 0, 0, 0);
    aA = __builtin_amdgcn_mfma_f32_32x32x16_bf16(a1t, b1, aA, 0, 0, 0);
    aS = __builtin_amdgcn_mfma_f32_32x32x16_bf16(a0s, b0, aS, 0, 0, 0);
    aS = __builtin_amdgcn_mfma_f32_32x32x16_bf16(a1s, b1, aS, 0, 0, 0);
  }

  // ---- gated activation -> zl ----
#pragma unroll
  for (int r = 0; r < 16; r += 2) {
    int ic0 = (r & 3) + 4 * hi + 8 * (r >> 2) + 32 * wv;  // even
    float z0 = (1.f - 2.f / (__expf(2.f * aA[r]) + 1.f)) *
               (1.f / (1.f + __expf(-aS[r])));
    float z1 = (1.f - 2.f / (__expf(2.f * aA[r + 1]) + 1.f)) *
               (1.f / (1.f + __expf(-aS[r + 1])));
    int p = (ic0 & ~15) | kpos(ic0 & 15);
    int tloc = l31;                                       // D col = t
    unsigned int byte = (unsigned int)(tloc * 128 + p * 2) ^
                        (unsigned int)((tloc & 7) << 4);
    *(unsigned int*)((char*)zl + byte) = pack2(z0, z1);
  }
  __syncthreads();

  // ---- skip partial: zg holds z (head does the K=1024 skip GEMM) ----
  {
    unsigned short* zb = zg + ((size_t)(blk * Bb + b) * TT + t0) * 64;
#pragma unroll
    for (int it = 0; it < 8; ++it) {
      int u = it * 128 + tid;          // 32 rows x 32 u32
      int p2 = u & 31, t = u >> 5;
      unsigned int byte = (unsigned int)(t * 128 + p2 * 4) ^
                          (unsigned int)((t & 7) << 4);
      unsigned int v = *(const unsigned int*)((char*)zl + byte);
      *(unsigned int*)(zb + (size_t)t * 64 + p2 * 2) = v;
    }
  }

  // ---- residual: rout = rs + z @ wres^T. D[row=t][col=oc] ----
  if (!last) {
    const int trow = l31;
    f32x16 ar = {};
    const short* wrb = wr + (size_t)blk * 4096 + (wv * 32 + l31) * 64;
#pragma unroll
    for (int ks = 0; ks < 4; ++ks) {
      int off = ks * 16 + 8 * hi;
      short8 az = *(const short8*)((char*)zl +
          ((unsigned int)(trow * 128 + off * 2) ^ (unsigned int)((trow & 7) << 4)));
      short8 bw = *(const short8*)(wrb + off);
      ar = __builtin_amdgcn_mfma_f32_32x32x16_bf16(az, bw, ar, 0, 0, 0);
    }
    float* obase = rout + (size_t)b * TT * 64;
    int oc = wv * 32 + l31;
#pragma unroll
    for (int r = 0; r < 16; ++r) {
      int t = (r & 3) + 4 * hi + 8 * (r >> 2);           // 0..31
      obase[(size_t)(t0 + t) * 64 + oc] = rs[t * 64 + oc] + ar[r];
    }
  }
}

// ---------------------------------------------------------------------------
// head: skip = sum_blk wsk_blk @ z_blk (K=1024, fp32 accum); y=relu;
// y2=relu(w1@y); out=w2@y2.  Tile 32, 256 thr (4 waves), grid (256, 4).
__global__ __launch_bounds__(256) void head_kernel(
    const unsigned short* __restrict__ zg, const short* __restrict__ wsk,
    const short* __restrict__ w1, const short* __restrict__ w2,
    float* __restrict__ out)
{
  __shared__ short zbuf[2][32 * 64];  // double-buffered z chunk, 2x4KB
  __shared__ short yb[32 * 256];      // [t][skp], 16KB
  __shared__ short y2b[32 * 256];     // [t][op],  16KB

  const int b = blockIdx.y;
  const int t0 = blockIdx.x * 32;
  const int tid = threadIdx.x;
  const int lane = tid & 63, wv = tid >> 6;   // wv in 0..3
  const int l31 = lane & 31, hi = lane >> 5;

  // prologue: stage z chunk for blk 0 (32 rows x 32 u32 = 1024)
  {
#pragma unroll
    for (int it = 0; it < 4; ++it) {
      int u = it * 256 + tid;
      int p2 = u & 31, t = u >> 5;
      unsigned int v = *(const unsigned int*)(zg +
          ((size_t)(0 * Bb + b) * TT + t0 + t) * 64 + p2 * 2);
      unsigned int byte = (unsigned int)(t * 128 + p2 * 4) ^
                          (unsigned int)((t & 7) << 4);
      *(unsigned int*)((char*)zbuf[0] + byte) = v;
    }
  }

  f32x16 acc0 = {}, acc1 = {};  // D[row=t][col=sk]; sk0=wv*32+l31, sk1=+128
  const short* wsb0 = wsk + (wv * 32 + l31) * 64;
  const short* wsb1 = wsk + ((wv + 4) * 32 + l31) * 64;

  for (int blk = 0; blk < NB; ++blk) {
    __syncthreads();
    if (blk < NB - 1) {
#pragma unroll
      for (int it = 0; it < 4; ++it) {
        int u = it * 256 + tid;
        int p2 = u & 31, t = u >> 5;
        unsigned int v = *(const unsigned int*)(zg +
            ((size_t)((blk + 1) * Bb + b) * TT + t0 + t) * 64 + p2 * 2);
        unsigned int byte = (unsigned int)(t * 128 + p2 * 4) ^
                            (unsigned int)((t & 7) << 4);
        *(unsigned int*)((char*)zbuf[(blk + 1) & 1] + byte) = v;
      }
    }
    const short* zb = zbuf[blk & 1];
#pragma unroll
    for (int ks = 0; ks < 4; ++ks) {
      int off = ks * 16 + 8 * hi;
      short8 bw0 = *(const short8*)(wsb0 + (size_t)blk * 16384 + off);
      short8 bw1 = *(const short8*)(wsb1 + (size_t)blk * 16384 + off);
      short8 az = *(const short8*)((char*)zb +
          ((unsigned int)(l31 * 128 + off * 2) ^ (unsigned int)((l31 & 7) << 4)));
      acc0 = __builtin_amdgcn_mfma_f32_32x32x16_bf16(az, bw0, acc0, 0, 0, 0);
      acc1 = __builtin_amdgcn_mfma_f32_32x32x16_bf16(az, bw1, acc1, 0, 0, 0);
    }
  }

  // relu -> yb [32][256] k-permuted swizzled
  {
    int sk0 = wv * 32 + l31;
    int sk1 = sk0 + 128;
    int p0 = (sk0 & 0xF0) | kpos(sk0 & 15);
    int p1 = (sk1 & 0xF0) | kpos(sk1 & 15);
#pragma unroll
    for (int r = 0; r < 16; ++r) {
      int dt = (r & 3) + 4 * hi + 8 * (r >> 2);          // 0..31
      unsigned int b0 = (unsigned int)(dt * 512 + p0 * 2) ^
                        (unsigned int)((dt & 7) << 4);
      unsigned int b1 = (unsigned int)(dt * 512 + p1 * 2) ^
                        (unsigned int)((dt & 7) << 4);
      *(short*)((char*)yb + b0) = (short)bf16_rn(fmaxf(acc0[r], 0.f));
      *(short*)((char*)yb + b1) = (short)bf16_rn(fmaxf(acc1[r], 0.f));
    }
  }
  __syncthreads();

  // y2 = relu(w1 @ y): D[row=o][col=t] -> y2b transposed [t][op]
#pragma unroll
  for (int ot = 0; ot < 2; ++ot) {
    const short* w1r = w1 + ((wv + 4 * ot) * 32 + l31) * 256;
    const int trow = l31;
    f32x16 acc = {};
#pragma unroll
    for (int ks = 0; ks < 16; ++ks) {
      int off = ks * 16 + 8 * hi;
      short8 by = *(const short8*)((char*)yb +
          ((unsigned int)(trow * 512 + off * 2) ^ (unsigned int)((trow & 7) << 4)));
      short8 aw = *(const short8*)(w1r + off);
      acc = __builtin_amdgcn_mfma_f32_32x32x16_bf16(aw, by, acc, 0, 0, 0);
    }
#pragma unroll
    for (int r = 0; r < 16; r += 2) {
      int o0 = (wv + 4 * ot) * 32 + (r & 3) + 4 * hi + 8 * (r >> 2);
      unsigned int v = (unsigned int)bf16_rn(fmaxf(acc[r], 0.f)) |
                       ((unsigned int)bf16_rn(fmaxf(acc[r + 1], 0.f)) << 16);
      int p = (o0 & 0xF0) | kpos(o0 & 15);
      unsigned int byte = (unsigned int)(trow * 512 + p * 2) ^
                          (unsigned int)((trow & 7) << 4);
      *(unsigned int*)((char*)y2b + byte) = v;
    }
  }
  __syncthreads();

  // out = w2 @ y2: D[row=oc][col=t], coalesced [B][OUT][T] write
  {
    float* ob = out + (size_t)b * 256 * TT;
#pragma unroll
    for (int ot = 0; ot < 2; ++ot) {
      const short* w2r = w2 + ((wv + 4 * ot) * 32 + l31) * 256;
      const int trow = l31;
      f32x16 acc = {};
#pragma unroll
      for (int ks = 0; ks < 16; ++ks) {
        int off = ks * 16 + 8 * hi;
        short8 by = *(const short8*)((char*)y2b +
            ((unsigned int)(trow * 512 + off * 2) ^ (unsigned int)((trow & 7) << 4)));
        short8 aw = *(const short8*)(w2r + off);
        acc = __builtin_amdgcn_mfma_f32_32x32x16_bf16(aw, by, acc, 0, 0, 0);
      }
#pragma unroll
      for (int r = 0; r < 16; ++r) {
        int oc = (wv + 4 * ot) * 32 + (r & 3) + 4 * hi + 8 * (r >> 2);
        ob[(size_t)oc * TT + t0 + trow] = acc[r];
      }
    }
  }
}

// ---------------------------------------------------------------------------
extern "C" void kernel_launch(void* const* d_in, const int* in_sizes, int n_in,
                              void* d_out, int out_size, void* d_ws, size_t ws_size,
                              hipStream_t stream)
{
  const int* x = (const int*)d_in[0];
  const float* h = (const float*)d_in[1];
  const float* embed = (const float*)d_in[2];
  const float* w_conv = (const float*)d_in[3];
  const float* w_res = (const float*)d_in[4];
  const float* w_skip = (const float*)d_in[5];
  const float* w_out1 = (const float*)d_in[6];
  const float* w_out2 = (const float*)d_in[7];
  float* out = (float*)d_out;

  char* ws = (char*)d_ws;
  float* resid0 = (float*)ws;                                   // 8 MB
  float* resid1 = (float*)(ws + (size_t)(8 << 20));             // 8 MB
  unsigned short* zg = (unsigned short*)(ws + (size_t)(16 << 20)); // 64 MB
  short* dwc = (short*)(ws + (size_t)(80 << 20));               // 512 KB
  short* dwr = dwc + 262144;
  short* dws = dwr + 65536;
  short* dw1 = dws + 262144;
  short* dw2 = dw1 + 65536;

  prep_weights<<<2816, 256, 0, stream>>>(w_conv, w_res, w_skip, w_out1, w_out2,
                                         dwc, dwr, dws, dw1, dw2);

  float* rf[2] = {resid0, resid1};
  const int dils[NB] = {1, 2, 4, 8, 16, 32, 64, 128,
                        1, 2, 4, 8, 16, 32, 64, 128};
  for (int i = 0; i < NB; ++i) {
    block_kernel<<<dim3(TT / 32, Bb), 128, 0, stream>>>(
        rf[i & 1], rf[(i + 1) & 1], x, embed, h, dwc, dwr, zg,
        i, dils[i], i == NB - 1);
  }

  head_kernel<<<dim3(TT / 32, Bb), 256, 0, stream>>>(zg, dws, dw1, dw2, out);
}